// Round 5
// baseline (310.270 us; speedup 1.0000x reference)
//
#include <hip/hip_runtime.h>
#include <hip/hip_bf16.h>
#include <cstddef>

#define B 32
#define S 512
#define D 1536
#define D24 64
#define EPS 1e-5f

typedef float float4v __attribute__((ext_vector_type(4)));
typedef short short8 __attribute__((ext_vector_type(8)));

__device__ __forceinline__ float gelu_exact(float v) {
    return 0.5f * v * (1.0f + erff(v * 0.70710678118654752440f));
}

// tanh-form gelu (epilogue only): max abs err ~1e-3 << 0.164 threshold.
__device__ __forceinline__ float gelu_fast(float v) {
    float u = v * v;
    float z = v * __builtin_fmaf(0.07135481627f, u, 1.5957691216f);
    return v / (1.0f + __expf(-z));
}

__device__ __forceinline__ unsigned short f2bf(float f) {
    union { float f; unsigned u; } x; x.f = f;
    unsigned r = x.u + 0x7fffu + ((x.u >> 16) & 1u);  // RNE
    return (unsigned short)(r >> 16);
}

// ---------------- Kernel 1: per-row LN stats (mu, rstd); one wave per row ----------------
__global__ __launch_bounds__(256) void stats_kernel(const float* __restrict__ x,
                                                    float* __restrict__ stats) {
    const int lane = threadIdx.x & 63;
    const int w    = threadIdx.x >> 6;
    const int row  = blockIdx.x * 4 + w;            // 4096 blocks x 4 waves
    const float4* xr = (const float4*)(x + (size_t)row * D);   // 384 float4
    float s1 = 0.f, s2 = 0.f;
#pragma unroll
    for (int j = 0; j < 6; j++) {
        float4 v = xr[lane + j * 64];
        s1 += v.x + v.y + v.z + v.w;
        s2 += v.x * v.x + v.y * v.y + v.z * v.z + v.w * v.w;
    }
#pragma unroll
    for (int off = 32; off > 0; off >>= 1) {
        s1 += __shfl_down(s1, off, 64);
        s2 += __shfl_down(s2, off, 64);
    }
    if (lane == 0) {
        float mu  = s1 * (1.0f / D);
        float var = s2 * (1.0f / D) - mu * mu;
        stats[row * 2 + 0] = mu;
        stats[row * 2 + 1] = rsqrtf(var + EPS);
    }
}

// ------- Kernel 2: normalize + transpose to xnT[b][d][t] (bf16) + transposed c slice (fp32) -------
__global__ __launch_bounds__(256) void nt_kernel(const float* __restrict__ x,
                                                 const float* __restrict__ stats,
                                                 const float* __restrict__ ln_g,
                                                 const float* __restrict__ ln_b,
                                                 unsigned short* __restrict__ xnT,
                                                 float* __restrict__ cbufT) {
    const int b  = blockIdx.z;
    const int t0 = blockIdx.y * 64;
    const int d0 = blockIdx.x * 64;
    const int tid = threadIdx.x;
    __shared__ float tile[64][65];                 // [t][d]

    // phase 1: coalesced float4 reads of x (L3-warm after stats), normalize, store [t][d]
    const int dq = (tid & 15) * 4;
    const int rg = tid >> 4;                       // 0..15
    float4 g4 = *(const float4*)(ln_g + d0 + dq);
    float4 b4 = *(const float4*)(ln_b + d0 + dq);
#pragma unroll
    for (int p = 0; p < 4; p++) {
        int row  = rg + p * 16;
        int grow = b * S + t0 + row;
        float mu   = stats[grow * 2 + 0];
        float rstd = stats[grow * 2 + 1];
        float4 v = *(const float4*)(x + (size_t)grow * D + d0 + dq);
        tile[row][dq + 0] = (v.x - mu) * rstd * g4.x + b4.x;
        tile[row][dq + 1] = (v.y - mu) * rstd * g4.y + b4.y;
        tile[row][dq + 2] = (v.z - mu) * rstd * g4.z + b4.z;
        tile[row][dq + 3] = (v.w - mu) * rstd * g4.w + b4.w;
    }
    __syncthreads();

    // phase 2: transposed 16B writes
    const int t8  = (tid & 7) * 8;
    const int dr0 = tid >> 3;                      // 0..31
    const bool write_c = (d0 == 0);
#pragma unroll
    for (int p = 0; p < 2; p++) {
        int drow = dr0 + p * 32;
        float fv[8];
        unsigned short bv[8];
#pragma unroll
        for (int j = 0; j < 8; j++) { fv[j] = tile[t8 + j][drow]; bv[j] = f2bf(fv[j]); }
        *(short8*)(xnT + ((size_t)b * D + d0 + drow) * S + t0 + t8) = *(const short8*)bv;
        if (write_c) {
            float* cp = cbufT + ((size_t)b * D24 + drow) * S + t0 + t8;
            *(float4*)(cp + 0) = (float4){fv[0], fv[1], fv[2], fv[3]};
            *(float4*)(cp + 4) = (float4){fv[4], fv[5], fv[6], fv[7]};
        }
    }
}

// ---------------- Kernel 3: convert Wi/Wii to bf16 (vectorized) ----------------
__global__ __launch_bounds__(256) void convw_kernel(const float* __restrict__ Wi,
                                                    const float* __restrict__ Wii,
                                                    unsigned short* __restrict__ wbf) {
    int i = (blockIdx.x * 256 + threadIdx.x) * 4;   // grid covers 2*512*512 floats
    const float* src = (i < S * S) ? (Wi + i) : (Wii + i - S * S);
    float4 v = *(const float4*)src;
    unsigned short o[4] = {f2bf(v.x), f2bf(v.y), f2bf(v.z), f2bf(v.w)};
    *(uint2*)(wbf + i) = *(const uint2*)o;
}

// ---------------- Kernel 4a: gating MLP stage A (coalesced over s) ----------------
__global__ __launch_bounds__(256) void gateA_kernel(const float* __restrict__ cbufT,
                                                    const float* __restrict__ w1,
                                                    const float* __restrict__ b1,
                                                    const float* __restrict__ wc,
                                                    float* __restrict__ partial) {
    const int b  = blockIdx.x >> 1;
    const int sb = blockIdx.x & 1;
    const int tid = threadIdx.x;
    const int s = sb * 256 + tid;
    __shared__ float w1s[D24 * 10];
    __shared__ float wsum[4][10];
    for (int i = tid; i < D24 * 10; i += 256) w1s[i] = w1[i];
    __syncthreads();

    float acc[10];
#pragma unroll
    for (int k = 0; k < 10; k++) acc[k] = b1[k];
    const float* cb = cbufT + (size_t)b * D24 * S + s;
#pragma unroll 8
    for (int i = 0; i < D24; i++) {
        float v = cb[(size_t)i * S];
#pragma unroll
        for (int k = 0; k < 10; k++) acc[k] += v * w1s[i * 10 + k];
    }
    float wcs = wc[s];
#pragma unroll
    for (int k = 0; k < 10; k++) {
        float t = gelu_exact(acc[k]) * wcs;
#pragma unroll
        for (int off = 32; off > 0; off >>= 1) t += __shfl_down(t, off, 64);
        if ((tid & 63) == 0) wsum[tid >> 6][k] = t;
    }
    __syncthreads();
    if (tid < 10)
        partial[blockIdx.x * 10 + tid] =
            wsum[0][tid] + wsum[1][tid] + wsum[2][tid] + wsum[3][tid];
}

// ---------------- Kernel 4b: gating MLP stage B -> sel[b] ----------------
__global__ __launch_bounds__(64) void gateB_kernel(const float* __restrict__ partial,
                                                   const float* __restrict__ bc,
                                                   const float* __restrict__ w2,
                                                   const float* __restrict__ b2,
                                                   int* __restrict__ sel) {
    int b = threadIdx.x;
    if (b < B) {
        float logit = b2[0];
        float bc0 = bc[0];
#pragma unroll
        for (int k = 0; k < 10; k++) {
            float ssum = partial[(b * 2) * 10 + k] + partial[(b * 2 + 1) * 10 + k];
            logit += gelu_exact(ssum + bc0) * w2[k];
        }
        sel[b] = (logit >= 0.f) ? 1 : 0;   // round(sigmoid(x)) == (x >= 0)
    }
}

// ---------------- Kernel 5: main GEMM + bias + residual + gelu ----------------
// out[b,s,d] = gelu( sum_t W[s,t]*xn[b,t,d] + bias[s] + x[b,s,d] )
// BK=32 double-buffered (32 KB LDS -> 4 blocks/CU, 16 waves/CU). 16B chunks
// XOR-swizzled with slot = c ^ ((row>>1)&3): fragment ds_read_b128 spreads each
// quarter-wave over all 8 bank-granule groups (2 lanes each -> conflict-free).
// Grid: s-tile fastest so the 4 blocks sharing an xnT slab are dispatch-adjacent.
__global__ __launch_bounds__(256) void gemm_kernel(const unsigned short* __restrict__ xnT,
                                                   const unsigned short* __restrict__ wbf,
                                                   const int* __restrict__ sel,
                                                   const float* __restrict__ bi,
                                                   const float* __restrict__ bii,
                                                   const float* __restrict__ x,
                                                   float* __restrict__ out) {
    const int b  = blockIdx.z;
    const int s0 = blockIdx.x * 128;   // s fastest
    const int d0 = blockIdx.y * 128;
    const int tid  = threadIdx.x;
    const int lane = tid & 63;
    const int wid  = tid >> 6;
    const int wm = (wid & 1) * 64;
    const int wn = (wid >> 1) * 64;
    const int q   = lane >> 4;
    const int r16 = lane & 15;

    const int ssel = sel[b];
    const unsigned short* W = wbf + (size_t)ssel * S * S;
    const float* bias = ssel ? bii : bi;
    const unsigned short* Xb = xnT + (size_t)b * D * S;

    __shared__ __align__(16) unsigned short As[2][128 * 32];  // 8 KB each buf
    __shared__ __align__(16) unsigned short Bs[2][128 * 32];

    // stage 128x32 tile pair into buffer bf: 2x256 lane-linear 16B chunks per array
    auto stage = [&](int k0, int bf) {
#pragma unroll
        for (int i = 0; i < 2; i++) {
            int L = i * 256 + tid;          // 16B-chunk index 0..511
            int row = L >> 2;               // 0..127
            int sc  = L & 3;                // stored chunk slot
            int c16 = sc ^ ((row >> 1) & 3);  // logical k-chunk in that slot
            const unsigned short* gaA = W  + (size_t)(s0 + row) * S + k0 + c16 * 8;
            const unsigned short* gaB = Xb + (size_t)(d0 + row) * S + k0 + c16 * 8;
            unsigned short* laA = As[bf] + (size_t)(i * 256 + wid * 64) * 8;  // wave-uniform base
            unsigned short* laB = Bs[bf] + (size_t)(i * 256 + wid * 64) * 8;
            __builtin_amdgcn_global_load_lds(
                (const __attribute__((address_space(1))) void*)gaA,
                (__attribute__((address_space(3))) void*)laA, 16, 0, 0);
            __builtin_amdgcn_global_load_lds(
                (const __attribute__((address_space(1))) void*)gaB,
                (__attribute__((address_space(3))) void*)laB, 16, 0, 0);
        }
    };

    float4v acc[4][4];
#pragma unroll
    for (int mi = 0; mi < 4; mi++)
#pragma unroll
        for (int ni = 0; ni < 4; ni++) acc[mi][ni] = (float4v){0.f, 0.f, 0.f, 0.f};

    stage(0, 0);
    __syncthreads();                       // drains tile-0 loads

    for (int it = 0; it < 16; it++) {
        const int cur = it & 1;
        if (it < 15) stage((it + 1) * 32, cur ^ 1);   // fire-and-forget prefetch

        const unsigned short* Ac = As[cur];
        const unsigned short* Bc = Bs[cur];
        short8 af[4], bfr[4];
#pragma unroll
        for (int mi = 0; mi < 4; mi++) {
            int row = wm + mi * 16 + r16;
            int slot = q ^ ((row >> 1) & 3);
            af[mi] = *(const short8*)(Ac + (row * 4 + slot) * 8);
        }
#pragma unroll
        for (int ni = 0; ni < 4; ni++) {
            int row = wn + ni * 16 + r16;
            int slot = q ^ ((row >> 1) & 3);
            bfr[ni] = *(const short8*)(Bc + (row * 4 + slot) * 8);
        }
#pragma unroll
        for (int mi = 0; mi < 4; mi++)
#pragma unroll
            for (int ni = 0; ni < 4; ni++)
                acc[mi][ni] = __builtin_amdgcn_mfma_f32_16x16x32_bf16(
                    af[mi], bfr[ni], acc[mi][ni], 0, 0, 0);
        __syncthreads();                   // drains the overlapped prefetch + guards reuse
    }

    // Epilogue: C/D layout col=lane&15, row=(lane>>4)*4+r ; fast gelu
#pragma unroll
    for (int mi = 0; mi < 4; mi++) {
        int srow = s0 + wm + mi * 16 + q * 4;
#pragma unroll
        for (int ni = 0; ni < 4; ni++) {
            int d = d0 + wn + ni * 16 + r16;
#pragma unroll
            for (int r = 0; r < 4; r++) {
                int ss = srow + r;
                size_t gi = ((size_t)b * S + ss) * D + d;
                float v = acc[mi][ni][r] + bias[ss] + x[gi];
                out[gi] = gelu_fast(v);
            }
        }
    }
}

extern "C" void kernel_launch(void* const* d_in, const int* in_sizes, int n_in,
                              void* d_out, int out_size, void* d_ws, size_t ws_size,
                              hipStream_t stream) {
    const float* x    = (const float*)d_in[0];
    const float* ln_g = (const float*)d_in[1];
    const float* ln_b = (const float*)d_in[2];
    const float* w1   = (const float*)d_in[3];
    const float* b1   = (const float*)d_in[4];
    const float* wc   = (const float*)d_in[5];
    const float* bc   = (const float*)d_in[6];
    const float* w2   = (const float*)d_in[7];
    const float* b2   = (const float*)d_in[8];
    const float* Wi   = (const float*)d_in[9];
    const float* bi   = (const float*)d_in[10];
    const float* Wii  = (const float*)d_in[11];
    const float* bii  = (const float*)d_in[12];
    float* out = (float*)d_out;

    char* ws = (char*)d_ws;
    const size_t XNT_BYTES   = (size_t)B * D * S * 2;        // 50331648
    const size_t STATS_BYTES = (size_t)B * S * 2 * 4;        // 131072
    const size_t C_BYTES     = (size_t)B * D24 * S * 4;      // 4194304 (transposed)
    const size_t WBF_BYTES   = (size_t)2 * S * S * 2;        // 1048576
    const size_t PART_BYTES  = (size_t)B * 2 * 10 * 4;       // 2560
    unsigned short* xnT   = (unsigned short*)ws;
    float*          stat  = (float*)(ws + XNT_BYTES);
    float*          cbufT = (float*)(ws + XNT_BYTES + STATS_BYTES);
    unsigned short* wbf   = (unsigned short*)(ws + XNT_BYTES + STATS_BYTES + C_BYTES);
    float*          part  = (float*)(ws + XNT_BYTES + STATS_BYTES + C_BYTES + WBF_BYTES);
    int*            sel   = (int*)(ws + XNT_BYTES + STATS_BYTES + C_BYTES + WBF_BYTES + PART_BYTES);

    stats_kernel<<<(B * S) / 4, 256, 0, stream>>>(x, stat);
    nt_kernel<<<dim3(D / 64, S / 64, B), 256, 0, stream>>>(x, stat, ln_g, ln_b, xnT, cbufT);
    convw_kernel<<<(2 * S * S) / 1024, 256, 0, stream>>>(Wi, Wii, wbf);
    gateA_kernel<<<B * 2, 256, 0, stream>>>(cbufT, w1, b1, wc, part);
    gateB_kernel<<<1, 64, 0, stream>>>(part, bc, w2, b2, sel);
    gemm_kernel<<<dim3(S / 128, D / 128, B), 256, 0, stream>>>(xnT, wbf, sel, bi, bii, x, out);
}

// Round 6
// 268.316 us; speedup vs baseline: 1.1564x; 1.1564x over previous
//
#include <hip/hip_runtime.h>
#include <hip/hip_bf16.h>
#include <cstddef>

#define B 32
#define S 512
#define D 1536
#define D24 64
#define EPS 1e-5f

typedef float float4v __attribute__((ext_vector_type(4)));
typedef short short8 __attribute__((ext_vector_type(8)));

__device__ __forceinline__ float gelu_exact(float v) {
    return 0.5f * v * (1.0f + erff(v * 0.70710678118654752440f));
}

// tanh-form gelu (epilogue only): max abs err ~1e-3 << 0.164 threshold.
__device__ __forceinline__ float gelu_fast(float v) {
    float u = v * v;
    float z = v * __builtin_fmaf(0.07135481627f, u, 1.5957691216f);
    return v / (1.0f + __expf(-z));
}

__device__ __forceinline__ unsigned short f2bf(float f) {
    union { float f; unsigned u; } x; x.f = f;
    unsigned r = x.u + 0x7fffu + ((x.u >> 16) & 1u);  // RNE
    return (unsigned short)(r >> 16);
}

// =============== Kernel A: LN(stats+normalize+transpose) + gate partials + convw ===============
// blocks 0..1023 : (b, t-tile of 16 rows). Stats over own rows, then 24 d-tiles of
//   16x64: normalize -> LDS -> transposed write to blocked xnT[b][t/16][d][t%16]
//   (2 KB contiguous per tile). At dt==0 the fp32 tile IS the gate's c-slice:
//   accumulate sum_s gelu(c.w1+b1)*wc[s] into part[b][10] via LDS + global atomicAdd.
// blocks 1024..1535 : convert Wi/Wii to bf16 (vectorized).
__global__ __launch_bounds__(256) void prep_kernel(const float* __restrict__ x,
                                                   const float* __restrict__ ln_g,
                                                   const float* __restrict__ ln_b,
                                                   const float* __restrict__ w1,
                                                   const float* __restrict__ b1,
                                                   const float* __restrict__ wc,
                                                   const float* __restrict__ Wi,
                                                   const float* __restrict__ Wii,
                                                   unsigned short* __restrict__ xnT,
                                                   unsigned short* __restrict__ wbf,
                                                   float* __restrict__ part) {
    const int blk = blockIdx.x;
    const int tid = threadIdx.x;

    if (blk >= 1024) {                       // ---- convw path ----
        int i = ((blk - 1024) * 256 + tid) * 4;
        const float* src = (i < S * S) ? (Wi + i) : (Wii + i - S * S);
        float4 v = *(const float4*)src;
        unsigned short o[4] = {f2bf(v.x), f2bf(v.y), f2bf(v.z), f2bf(v.w)};
        *(uint2*)(wbf + i) = *(const uint2*)o;
        return;
    }

    const int b    = blk >> 5;               // 0..31
    const int tile = blk & 31;               // t-tile 0..31
    const int t0   = tile * 16;
    const int lane = tid & 63;
    const int w    = tid >> 6;

    __shared__ float tl[16][65];             // [t_local][d_local]
    __shared__ float lmu[16], lrs[16];
    __shared__ float w1s[D24 * 10];
    __shared__ float lds_part[10];

    for (int i = tid; i < D24 * 10; i += 256) w1s[i] = w1[i];
    if (tid < 10) lds_part[tid] = 0.f;

    // ---- stats: wave w handles rows 4w..4w+3 ----
    for (int r = 0; r < 4; r++) {
        int row = w * 4 + r;
        const float4* xr = (const float4*)(x + (size_t)(b * S + t0 + row) * D);
        float s1 = 0.f, s2 = 0.f;
#pragma unroll
        for (int j = 0; j < 6; j++) {
            float4 v = xr[lane + j * 64];
            s1 += v.x + v.y + v.z + v.w;
            s2 += v.x * v.x + v.y * v.y + v.z * v.z + v.w * v.w;
        }
#pragma unroll
        for (int off = 32; off > 0; off >>= 1) {
            s1 += __shfl_down(s1, off, 64);
            s2 += __shfl_down(s2, off, 64);
        }
        if (lane == 0) {
            float mu  = s1 * (1.0f / D);
            float var = s2 * (1.0f / D) - mu * mu;
            lmu[row] = mu;
            lrs[row] = rsqrtf(var + EPS);
        }
    }
    __syncthreads();

    // ---- 24 d-tiles of 16x64: normalize + transpose (+ gate at dt==0) ----
    const int rrow = tid >> 4;               // 0..15
    const int dq   = (tid & 15) * 4;
    const int drow = tid >> 1;               // 0..127 (writer: tid<128)
    const int t8   = (tid & 1) * 8;

    for (int dt = 0; dt < 24; dt++) {
        const int d0 = dt * 64;
        {
            float4 g4 = *(const float4*)(ln_g + d0 + dq);
            float4 b4 = *(const float4*)(ln_b + d0 + dq);
            float mu = lmu[rrow], rstd = lrs[rrow];
            float4 v = *(const float4*)(x + (size_t)(b * S + t0 + rrow) * D + d0 + dq);
            tl[rrow][dq + 0] = (v.x - mu) * rstd * g4.x + b4.x;
            tl[rrow][dq + 1] = (v.y - mu) * rstd * g4.y + b4.y;
            tl[rrow][dq + 2] = (v.z - mu) * rstd * g4.z + b4.z;
            tl[rrow][dq + 3] = (v.w - mu) * rstd * g4.w + b4.w;
        }
        __syncthreads();
        if (tid < 128) {
            unsigned short bv[8];
#pragma unroll
            for (int j = 0; j < 8; j++) bv[j] = f2bf(tl[t8 + j][drow]);
            // blocked layout: [b][tile][d][16 t] ; 128 threads x 16B = 2 KB contiguous
            *(short8*)(xnT + (((size_t)(b * 32 + tile)) * D + d0 + drow) * 16 + t8) =
                *(const short8*)bv;
        }
        if (dt == 0 && tid < 160) {          // gate partial: (s,k) = (tid/10, tid%10)
            int s_l = tid / 10, k = tid - s_l * 10;
            float d = b1[k];
#pragma unroll
            for (int i = 0; i < D24; i++) d += tl[s_l][i] * w1s[i * 10 + k];
            atomicAdd(&lds_part[k], gelu_exact(d) * wc[t0 + s_l]);
        }
        __syncthreads();
        if (dt == 0 && tid < 10) atomicAdd(part + b * 10 + tid, lds_part[tid]);
    }
}

// =============== Kernel B: GEMM + bias + residual + gelu (R4 structure) ===============
// out[b,s,d] = gelu( sum_t W[sel[b]][s,t]*xn[b,t,d] + bias[s] + x[b,s,d] )
// sel computed per-block from part[] (10 exact-erf gelus, trivial).
// BK=64 double-buffered; prefetch issued right after the barrier runs the whole
// compute phase in flight. 16B chunks XOR-swizzled (conflict-free, verified R3/R4).
__global__ __launch_bounds__(256, 2) void gemm_kernel(const unsigned short* __restrict__ xnT,
                                                      const unsigned short* __restrict__ wbf,
                                                      const float* __restrict__ part,
                                                      const float* __restrict__ bc,
                                                      const float* __restrict__ w2,
                                                      const float* __restrict__ b2,
                                                      const float* __restrict__ bi,
                                                      const float* __restrict__ bii,
                                                      const float* __restrict__ x,
                                                      float* __restrict__ out) {
    const int b  = blockIdx.z;
    const int s0 = blockIdx.y * 128;
    const int d0 = blockIdx.x * 128;   // d fastest (R4: better L2 FETCH)
    const int tid  = threadIdx.x;
    const int lane = tid & 63;
    const int wid  = tid >> 6;
    const int wm = (wid & 1) * 64;
    const int wn = (wid >> 1) * 64;
    const int q   = lane >> 4;
    const int r16 = lane & 15;

    // ---- gate decision (uniform across block; part is L2-hot) ----
    float logit = b2[0];
    {
        float bc0 = bc[0];
        const float* pb = part + b * 10;
#pragma unroll
        for (int k = 0; k < 10; k++) logit += gelu_exact(pb[k] + bc0) * w2[k];
    }
    const int ssel = (logit >= 0.f) ? 1 : 0;
    const unsigned short* W = wbf + (size_t)ssel * S * S;
    const float* bias = ssel ? bii : bi;
    const unsigned short* Xb = xnT + (size_t)b * D * S;   // blocked [tile][d][16]

    __shared__ __align__(16) unsigned short As[2][128 * 64];  // [row][64k], swizzled chunks
    __shared__ __align__(16) unsigned short Bs[2][128 * 64];

    auto stage = [&](int k0, int bf) {
#pragma unroll
        for (int i = 0; i < 4; i++) {
            int L = i * 256 + tid;          // 16B-chunk index 0..1023
            int row = L >> 3;               // 0..127
            int sc  = L & 7;                // stored chunk slot
            int c16 = sc ^ (row & 7);       // logical k-chunk in that slot
            int t_abs = k0 + c16 * 8;
            const unsigned short* gaA = W + (size_t)(s0 + row) * S + t_abs;
            const unsigned short* gaB =
                Xb + ((size_t)(t_abs >> 4) * D + (d0 + row)) * 16 + (t_abs & 15);
            unsigned short* laA = As[bf] + (size_t)(i * 256 + wid * 64) * 8;  // wave-uniform base
            unsigned short* laB = Bs[bf] + (size_t)(i * 256 + wid * 64) * 8;
            __builtin_amdgcn_global_load_lds(
                (const __attribute__((address_space(1))) void*)gaA,
                (__attribute__((address_space(3))) void*)laA, 16, 0, 0);
            __builtin_amdgcn_global_load_lds(
                (const __attribute__((address_space(1))) void*)gaB,
                (__attribute__((address_space(3))) void*)laB, 16, 0, 0);
        }
    };

    float4v acc[4][4];
#pragma unroll
    for (int mi = 0; mi < 4; mi++)
#pragma unroll
        for (int ni = 0; ni < 4; ni++) acc[mi][ni] = (float4v){0.f, 0.f, 0.f, 0.f};

    stage(0, 0);
    __syncthreads();                       // drains tile-0 loads

    for (int it = 0; it < 8; it++) {
        const int cur = it & 1;
        if (it < 7) stage((it + 1) * 64, cur ^ 1);   // fire-and-forget prefetch

        const unsigned short* Ac = As[cur];
        const unsigned short* Bc = Bs[cur];
#pragma unroll
        for (int h = 0; h < 2; h++) {
            short8 af[4], bfr[4];
#pragma unroll
            for (int mi = 0; mi < 4; mi++) {
                int row = wm + mi * 16 + r16;
                af[mi] = *(const short8*)(Ac + row * 64 + (((h << 2) + q) ^ (r16 & 7)) * 8);
            }
#pragma unroll
            for (int ni = 0; ni < 4; ni++) {
                int row = wn + ni * 16 + r16;
                bfr[ni] = *(const short8*)(Bc + row * 64 + (((h << 2) + q) ^ (r16 & 7)) * 8);
            }
#pragma unroll
            for (int mi = 0; mi < 4; mi++)
#pragma unroll
                for (int ni = 0; ni < 4; ni++)
                    acc[mi][ni] = __builtin_amdgcn_mfma_f32_16x16x32_bf16(
                        af[mi], bfr[ni], acc[mi][ni], 0, 0, 0);
        }
        __syncthreads();                   // drains the overlapped prefetch + guards reuse
    }

    // Epilogue: C/D layout col=lane&15, row=(lane>>4)*4+r ; fast gelu
#pragma unroll
    for (int mi = 0; mi < 4; mi++) {
        int srow = s0 + wm + mi * 16 + q * 4;
#pragma unroll
        for (int ni = 0; ni < 4; ni++) {
            int d = d0 + wn + ni * 16 + r16;
#pragma unroll
            for (int r = 0; r < 4; r++) {
                int ss = srow + r;
                size_t gi = ((size_t)b * S + ss) * D + d;
                float v = acc[mi][ni][r] + bias[ss] + x[gi];
                out[gi] = gelu_fast(v);
            }
        }
    }
}

extern "C" void kernel_launch(void* const* d_in, const int* in_sizes, int n_in,
                              void* d_out, int out_size, void* d_ws, size_t ws_size,
                              hipStream_t stream) {
    const float* x    = (const float*)d_in[0];
    const float* ln_g = (const float*)d_in[1];
    const float* ln_b = (const float*)d_in[2];
    const float* w1   = (const float*)d_in[3];
    const float* b1   = (const float*)d_in[4];
    const float* wc   = (const float*)d_in[5];
    const float* bc   = (const float*)d_in[6];
    const float* w2   = (const float*)d_in[7];
    const float* b2   = (const float*)d_in[8];
    const float* Wi   = (const float*)d_in[9];
    const float* bi   = (const float*)d_in[10];
    const float* Wii  = (const float*)d_in[11];
    const float* bii  = (const float*)d_in[12];
    float* out = (float*)d_out;

    char* ws = (char*)d_ws;
    const size_t XNT_BYTES = (size_t)B * D * S * 2;        // 50331648
    const size_t WBF_BYTES = (size_t)2 * S * S * 2;        // 1048576
    unsigned short* xnT  = (unsigned short*)ws;
    unsigned short* wbf  = (unsigned short*)(ws + XNT_BYTES);
    float*          part = (float*)(ws + XNT_BYTES + WBF_BYTES);

    hipMemsetAsync(part, 0, (size_t)B * 10 * sizeof(float), stream);
    prep_kernel<<<1536, 256, 0, stream>>>(x, ln_g, ln_b, w1, b1, wc, Wi, Wii,
                                          xnT, wbf, part);
    gemm_kernel<<<dim3(D / 128, S / 128, B), 256, 0, stream>>>(
        xnT, wbf, part, bc, w2, b2, bi, bii, x, out);
}